// Round 7
// baseline (10408.800 us; speedup 1.0000x reference)
//
#include <hip/hip_runtime.h>
#include <hip/hip_fp16.h>

typedef _Float16 h8 __attribute__((ext_vector_type(8)));
typedef _Float16 h4 __attribute__((ext_vector_type(4)));
typedef float f4 __attribute__((ext_vector_type(4)));

#define DEV __device__ __forceinline__

constexpr unsigned kNumBlk = 512u;   // 2 blocks/CU
constexpr int kFrontSz = 32 * 32 * 512;  // halfs per frontier buffer

DEV float sigm(float x) { return 1.f / (1.f + __expf(-x)); }
DEV float tanhfast(float x) {
    x = fminf(fmaxf(x, -15.f), 15.f);
    float e = __expf(2.f * x);
    return (e - 1.f) / (e + 1.f);
}
DEV h8 h8zero() {
    h8 v;
#pragma unroll
    for (int e = 0; e < 8; ++e) v[e] = (_Float16)0.f;
    return v;
}

// ---------------- hierarchical grid barrier ----------------
// bar[0..7]=group counters (64 blocks each), bar[8]=root, bar[9]=generation.
// RELAXED polls (no cache inv); one ACQUIRE per block per barrier on exit.
DEV void gbar(unsigned* bar, int grp) {
    __syncthreads();
    if (threadIdx.x == 0) {
        __threadfence();  // release this block's prior stores
        unsigned g = __hip_atomic_load(&bar[9], __ATOMIC_RELAXED, __HIP_MEMORY_SCOPE_AGENT);
        unsigned p = __hip_atomic_fetch_add(&bar[grp], 1u, __ATOMIC_ACQ_REL, __HIP_MEMORY_SCOPE_AGENT);
        if (p == 63u) {
            __hip_atomic_store(&bar[grp], 0u, __ATOMIC_RELAXED, __HIP_MEMORY_SCOPE_AGENT);
            unsigned r = __hip_atomic_fetch_add(&bar[8], 1u, __ATOMIC_ACQ_REL, __HIP_MEMORY_SCOPE_AGENT);
            if (r == 7u) {
                __hip_atomic_store(&bar[8], 0u, __ATOMIC_RELAXED, __HIP_MEMORY_SCOPE_AGENT);
                __hip_atomic_store(&bar[9], g + 1u, __ATOMIC_RELEASE, __HIP_MEMORY_SCOPE_AGENT);
            }
        }
        unsigned cur;
        do {
            __builtin_amdgcn_s_sleep(2);
            cur = __hip_atomic_load(&bar[9], __ATOMIC_RELAXED, __HIP_MEMORY_SCOPE_AGENT);
        } while (cur == g);
        (void)__hip_atomic_load(&bar[9], __ATOMIC_ACQUIRE, __HIP_MEMORY_SCOPE_AGENT);
    }
    __syncthreads();
}

__global__ void k_zero(unsigned* ptr, int n) {
    int i = blockIdx.x * 256 + threadIdx.x;
    if (i < n) ptr[i] = 0u;
}

// ---------------- fp32 -> fp16 cast (embW) ----------------
__global__ void k_cast_f2h(const float* __restrict__ in, _Float16* __restrict__ out, int n4) {
    int i = blockIdx.x * blockDim.x + threadIdx.x;
    if (i < n4) {
        float4 v = reinterpret_cast<const float4*>(in)[i];
        h4 o;
        o[0] = (_Float16)v.x; o[1] = (_Float16)v.y; o[2] = (_Float16)v.z; o[3] = (_Float16)v.w;
        reinterpret_cast<h4*>(out)[i] = o;
    }
}

// ---------------- pack W_ext [4096][1280] ----------------
// row n: g=n>>10 (0=r,1=z,2=hn,3=inn), kk=n&1023
// col k: k<1024 -> h_prev part (W_hh), k>=1024 -> e part (W_ih)
__global__ void k_pack_wext(const float* __restrict__ Wih, const float* __restrict__ Whh,
                            _Float16* __restrict__ Wext) {
    int n = blockIdx.x, g = n >> 10, kk = n & 1023;
#pragma unroll
    for (int it = 0; it < 5; ++it) {
        int k = it * 256 + threadIdx.x;
        float v;
        if (k < 1024) v = (g == 3) ? 0.f : Whh[(size_t)(g * 1024 + kk) * 1024 + k];
        else          v = (g == 2) ? 0.f : Wih[(size_t)((g == 3 ? 2048 + kk : g * 1024 + kk)) * 256 + (k - 1024)];
        Wext[(size_t)n * 1280 + k] = (_Float16)v;
    }
}

// ---------------- pack compW_ext [512][1280] = [compW | resW] ----------------
__global__ void k_pack_cwext(const float* __restrict__ compW, const float* __restrict__ resW,
                             _Float16* __restrict__ cWext) {
    int n = blockIdx.x;
#pragma unroll
    for (int it = 0; it < 5; ++it) {
        int k = it * 256 + threadIdx.x;
        float v = (k < 1024) ? compW[(size_t)n * 1024 + k] : resW[(size_t)n * 256 + (k - 1024)];
        cWext[(size_t)n * 1280 + k] = (_Float16)v;
    }
}

// ---------------- e-GEMM: e[M][256] = x[M][256] @ embW[256][256]^T + embb ----
__global__ __launch_bounds__(256, 1) void k_gemm_a32(
    const float* __restrict__ A, const _Float16* __restrict__ W,
    const float* __restrict__ bias, _Float16* __restrict__ C,
    int M, int N, int K, int Ntiles) {
    __shared__ __align__(16) _Float16 sA[128 * 72];
    __shared__ __align__(16) _Float16 sB[128 * 72];
    int tm = blockIdx.x / Ntiles, tn = blockIdx.x % Ntiles;
    int tid = threadIdx.x, lane = tid & 63, w = tid >> 6;
    int wr = w >> 1, wc = w & 1;
    f4 acc[4][4] = {};
    for (int k0 = 0; k0 < K; k0 += 64) {
#pragma unroll
        for (int p = 0; p < 4; ++p) {
            int ch = tid + p * 256;
            int r = ch >> 3, cc = ch & 7;
            const float* ap = A + (size_t)(tm * 128 + r) * K + k0 + cc * 8;
            float4 v0 = *reinterpret_cast<const float4*>(ap);
            float4 v1 = *reinterpret_cast<const float4*>(ap + 4);
            h8 va;
            va[0] = (_Float16)v0.x; va[1] = (_Float16)v0.y; va[2] = (_Float16)v0.z; va[3] = (_Float16)v0.w;
            va[4] = (_Float16)v1.x; va[5] = (_Float16)v1.y; va[6] = (_Float16)v1.z; va[7] = (_Float16)v1.w;
            *reinterpret_cast<h8*>(sA + r * 72 + cc * 8) = va;
            h8 vb = *reinterpret_cast<const h8*>(W + (size_t)(tn * 128 + r) * K + k0 + cc * 8);
            *reinterpret_cast<h8*>(sB + r * 72 + cc * 8) = vb;
        }
        __syncthreads();
#pragma unroll
        for (int kc = 0; kc < 2; ++kc) {
            int ro = lane & 15;
            int ko = kc * 32 + (lane >> 4) * 8;
            h8 af[4], bf[4];
#pragma unroll
            for (int mf = 0; mf < 4; ++mf)
                af[mf] = *reinterpret_cast<const h8*>(sA + (wr * 64 + mf * 16 + ro) * 72 + ko);
#pragma unroll
            for (int nf = 0; nf < 4; ++nf)
                bf[nf] = *reinterpret_cast<const h8*>(sB + (wc * 64 + nf * 16 + ro) * 72 + ko);
#pragma unroll
            for (int mf = 0; mf < 4; ++mf)
#pragma unroll
                for (int nf = 0; nf < 4; ++nf)
                    acc[mf][nf] = __builtin_amdgcn_mfma_f32_16x16x32_f16(af[mf], bf[nf], acc[mf][nf], 0, 0, 0);
        }
        __syncthreads();
    }
#pragma unroll
    for (int nf = 0; nf < 4; ++nf) {
        int col = tn * 128 + wc * 64 + nf * 16 + (lane & 15);
        float bs = bias[col];
#pragma unroll
        for (int mf = 0; mf < 4; ++mf) {
#pragma unroll
            for (int q = 0; q < 4; ++q) {
                int row = tm * 128 + wr * 64 + mf * 16 + (lane >> 4) * 4 + q;
                C[(size_t)row * N + col] = (_Float16)(acc[mf][nf][q] + bs);
            }
        }
    }
}

// ---------------- recurrent kernel (double-buffered, 512 blocks) ----------------
struct SA { _Float16 A[2][64 * 72]; _Float16 B[2][128 * 72]; };  // 55,296 B
struct SB { _Float16 A[2][32 * 72]; _Float16 B[2][32 * 72]; float red[4][32][2]; };
union __align__(16) SM { SA a; SB b; };

__global__ __launch_bounds__(256, 2) void k_recur(
    const _Float16* __restrict__ e_h,    // [32768][256] token=(b*32+i)*32+j
    const _Float16* __restrict__ Wext,   // [4096][1280]
    const _Float16* __restrict__ cWext,  // [512][1280]
    const float* __restrict__ bih, const float* __restrict__ bhh,    // [3072]
    const float* __restrict__ compb, const float* __restrict__ resb, // [512]
    const float* __restrict__ lng, const float* __restrict__ lnb,    // [512]
    _Float16* __restrict__ hbuf,         // [cell][b][1024]
    _Float16* __restrict__ Hfront,       // [2][32 cells][32 b][512] fp16 frontier
    float* __restrict__ out,             // [b][i][j][512]
    float* __restrict__ hfinal,          // [b][512]
    unsigned* bar,                       // [10]
    unsigned* ctr,                       // [63][32]
    float* gred) {                       // [63][32][32][2]
    __shared__ SM sm;
    const int tid = threadIdx.x, lane = tid & 63, w = tid >> 6;
    const int lane15 = lane & 15, hi = lane >> 4;
    const int bid = blockIdx.x, grp = bid >> 6;

    for (int d = 0; d < 63; ++d) {
        const int i0 = d > 31 ? d - 31 : 0;
        const int i1 = d < 31 ? d : 31;
        const int ncells = i1 - i0 + 1;
        const int i0p = d > 32 ? d - 32 : 0;  // i0 of diag d-1
        const _Float16* Hprev = Hfront + ((d & 1) ^ 1) * kFrontSz;
        _Float16* Hcur = Hfront + (d & 1) * kFrontSz;

        // ===== phase A: gates GEMM (K=1280, N=4096) + GRU update -> hbuf =====
        const int Mt2 = (ncells + 1) >> 1;  // 64-row tiles (2 cells)
        if (bid < Mt2 * 32) {
            const int s = bid & 31;   // 32-col gate slice
            const int mt = bid >> 5;
            f4 acc[8] = {};
            h8 ra[2], rb[4];
            auto issue = [&](int kt) {
                int k0 = kt * 64;
#pragma unroll
                for (int p = 0; p < 2; ++p) {
                    int ch = tid + p * 256;
                    int r = ch >> 3, cc = ch & 7;
                    int m = mt * 64 + r;
                    int c = m >> 5; if (c >= ncells) c = ncells - 1;
                    int b = m & 31;
                    int i = i0 + c, j = d - i;
                    int k = k0 + cc * 8;
                    if (k < 512) {
                        ra[p] = (i > 0) ? *reinterpret_cast<const h8*>(
                                    Hprev + (((size_t)((i - 1 - i0p) * 32 + b)) << 9) + k)
                                        : h8zero();
                    } else if (k < 1024) {
                        ra[p] = (j > 0) ? *reinterpret_cast<const h8*>(
                                    Hprev + (((size_t)((i - i0p) * 32 + b)) << 9) + (k - 512))
                                        : h8zero();
                    } else {
                        ra[p] = *reinterpret_cast<const h8*>(
                            e_h + (((size_t)((b * 32 + i) * 32 + j)) << 8) + (k - 1024));
                    }
                }
#pragma unroll
                for (int p = 0; p < 4; ++p) {
                    int ch = tid + p * 256;
                    int rr = ch >> 3, cc = ch & 7;
                    int n = (rr >> 5) * 1024 + s * 32 + (rr & 31);
                    rb[p] = *reinterpret_cast<const h8*>(Wext + (size_t)n * 1280 + k0 + cc * 8);
                }
            };
            auto commit = [&](int buf) {
#pragma unroll
                for (int p = 0; p < 2; ++p) {
                    int ch = tid + p * 256;
                    int r = ch >> 3, cc = ch & 7;
                    *reinterpret_cast<h8*>(sm.a.A[buf] + r * 72 + cc * 8) = ra[p];
                }
#pragma unroll
                for (int p = 0; p < 4; ++p) {
                    int ch = tid + p * 256;
                    int rr = ch >> 3, cc = ch & 7;
                    *reinterpret_cast<h8*>(sm.a.B[buf] + rr * 72 + cc * 8) = rb[p];
                }
            };
            issue(0); commit(0); __syncthreads();
            for (int kt = 0; kt < 20; ++kt) {
                int cur = kt & 1;
                if (kt < 19) issue(kt + 1);
#pragma unroll
                for (int kc = 0; kc < 2; ++kc) {
                    int ko = kc * 32 + hi * 8;
                    h8 af = *reinterpret_cast<const h8*>(sm.a.A[cur] + (w * 16 + lane15) * 72 + ko);
#pragma unroll
                    for (int nf = 0; nf < 8; ++nf) {
                        h8 bf = *reinterpret_cast<const h8*>(
                            sm.a.B[cur] + ((nf >> 1) * 32 + (nf & 1) * 16 + lane15) * 72 + ko);
                        acc[nf] = __builtin_amdgcn_mfma_f32_16x16x32_f16(af, bf, acc[nf], 0, 0, 0);
                    }
                }
                if (kt < 19) { commit(cur ^ 1); __syncthreads(); }
            }
            // epilogue: fused gates, write h -> hbuf
            int rbase = mt * 64 + w * 16 + hi * 4;
            int c = (rbase >> 5);
            if (c < ncells) {
                int i = i0 + c, j = d - i;
#pragma unroll
                for (int q = 0; q < 4; ++q) {
                    int b = (rbase + q) & 31;
#pragma unroll
                    for (int u = 0; u < 2; ++u) {
                        int kk = s * 32 + u * 16 + lane15;
                        float r_ = sigm(acc[u][q] + bih[kk] + bhh[kk]);
                        float z_ = sigm(acc[2 + u][q] + bih[1024 + kk] + bhh[1024 + kk]);
                        float hn_ = acc[4 + u][q] + bhh[2048 + kk];
                        float in_ = acc[6 + u][q] + bih[2048 + kk];
                        float hp;
                        if (kk < 512)
                            hp = (i > 0) ? (float)Hprev[(((size_t)((i - 1 - i0p) * 32 + b)) << 9) + kk] : 0.f;
                        else
                            hp = (j > 0) ? (float)Hprev[(((size_t)((i - i0p) * 32 + b)) << 9) + kk - 512] : 0.f;
                        float n_ = tanhfast(in_ + r_ * hn_);
                        float h_ = (1.f - z_) * n_ + z_ * hp;
                        hbuf[(((size_t)(c * 32 + b)) << 10) + kk] = (_Float16)h_;
                    }
                }
            }
        }
        gbar(bar, grp);

        // ===== phase B: hc = [h|e] @ cWext^T, 16 slices x 32 cols, LN via atomics =====
        if (bid < ncells * 16) {
            const int c = bid >> 4, sl = bid & 15;
            const int i = i0 + c, j = d - i;
            const int mf = w >> 1, nf = w & 1;
            f4 acc = {};
            h8 rA, rB;
            auto issueB = [&](int kt) {
                int k0 = kt * 64;
                int r = tid >> 3, cc = tid & 7;
                int k = k0 + cc * 8;
                rA = (k < 1024)
                    ? *reinterpret_cast<const h8*>(hbuf + (((size_t)(c * 32 + r)) << 10) + k)
                    : *reinterpret_cast<const h8*>(e_h + (((size_t)((r * 32 + i) * 32 + j)) << 8) + (k - 1024));
                rB = *reinterpret_cast<const h8*>(cWext + (size_t)(sl * 32 + r) * 1280 + k0 + cc * 8);
            };
            auto commitB = [&](int buf) {
                int r = tid >> 3, cc = tid & 7;
                *reinterpret_cast<h8*>(sm.b.A[buf] + r * 72 + cc * 8) = rA;
                *reinterpret_cast<h8*>(sm.b.B[buf] + r * 72 + cc * 8) = rB;
            };
            issueB(0); commitB(0); __syncthreads();
            for (int kt = 0; kt < 20; ++kt) {
                int cur = kt & 1;
                if (kt < 19) issueB(kt + 1);
#pragma unroll
                for (int kc = 0; kc < 2; ++kc) {
                    int ko = kc * 32 + hi * 8;
                    h8 af = *reinterpret_cast<const h8*>(sm.b.A[cur] + (mf * 16 + lane15) * 72 + ko);
                    h8 bf = *reinterpret_cast<const h8*>(sm.b.B[cur] + (nf * 16 + lane15) * 72 + ko);
                    acc = __builtin_amdgcn_mfma_f32_16x16x32_f16(af, bf, acc, 0, 0, 0);
                }
                if (kt < 19) { commitB(cur ^ 1); __syncthreads(); }
            }
            // LN partials
            int col = sl * 32 + nf * 16 + lane15;
            float cb = compb[col] + resb[col];
            float s1v[4], s2v[4];
#pragma unroll
            for (int q = 0; q < 4; ++q) {
                float v = acc[q] + cb;
                acc[q] = v;
                s1v[q] = v; s2v[q] = v * v;
            }
#pragma unroll
            for (int off = 1; off < 16; off <<= 1)
#pragma unroll
                for (int q = 0; q < 4; ++q) {
                    s1v[q] += __shfl_xor(s1v[q], off, 64);
                    s2v[q] += __shfl_xor(s2v[q], off, 64);
                }
            if (lane15 == 0)
#pragma unroll
                for (int q = 0; q < 4; ++q) {
                    int b = mf * 16 + hi * 4 + q;
                    sm.b.red[w][b][0] = s1v[q];
                    sm.b.red[w][b][1] = s2v[q];
                }
            __syncthreads();
            size_t gbase = (((size_t)d * 32 + c) << 6);
            if (tid < 32) {
                int b = tid, wb = (b >> 4) * 2;
                float t1 = sm.b.red[wb][b][0] + sm.b.red[wb + 1][b][0];
                float t2 = sm.b.red[wb][b][1] + sm.b.red[wb + 1][b][1];
                atomicAdd(&gred[gbase + b * 2 + 0], t1);
                atomicAdd(&gred[gbase + b * 2 + 1], t2);
            }
            if (tid == 0) {
                __hip_atomic_fetch_add(&ctr[d * 32 + c], 1u, __ATOMIC_RELEASE, __HIP_MEMORY_SCOPE_AGENT);
                unsigned cur;
                do {
                    __builtin_amdgcn_s_sleep(2);
                    cur = __hip_atomic_load(&ctr[d * 32 + c], __ATOMIC_RELAXED, __HIP_MEMORY_SCOPE_AGENT);
                } while (cur < 16u);
                (void)__hip_atomic_load(&ctr[d * 32 + c], __ATOMIC_ACQUIRE, __HIP_MEMORY_SCOPE_AGENT);
            }
            __syncthreads();
            float lg = lng[col], lb = lnb[col];
#pragma unroll
            for (int q = 0; q < 4; ++q) {
                int b = mf * 16 + hi * 4 + q;
                float t1 = gred[gbase + b * 2 + 0];
                float t2 = gred[gbase + b * 2 + 1];
                float mu = t1 * (1.f / 512.f);
                float var = t2 * (1.f / 512.f) - mu * mu;
                float rstd = rsqrtf(var + 1e-5f);
                float y = (acc[q] - mu) * rstd * lg + lb;
                out[(((size_t)((b * 32 + i) * 32 + j)) << 9) + col] = y;
                Hcur[(((size_t)(c * 32 + b)) << 9) + col] = (_Float16)y;
                if (i == 31 && j == 31) hfinal[((size_t)b << 9) + col] = y;
            }
        }
        gbar(bar, grp);
    }
}

extern "C" void kernel_launch(void* const* d_in, const int* in_sizes, int n_in,
                              void* d_out, int out_size, void* d_ws, size_t ws_size,
                              hipStream_t stream) {
    const float* x = (const float*)d_in[0];
    const float* embW = (const float*)d_in[1];
    const float* embb = (const float*)d_in[2];
    const float* Wih = (const float*)d_in[3];
    const float* bih = (const float*)d_in[4];
    const float* Whh = (const float*)d_in[5];
    const float* bhh = (const float*)d_in[6];
    const float* compW = (const float*)d_in[7];
    const float* compb = (const float*)d_in[8];
    const float* resW = (const float*)d_in[9];
    const float* resb = (const float*)d_in[10];
    const float* lng = (const float*)d_in[11];
    const float* lnb = (const float*)d_in[12];
    float* out = (float*)d_out;
    float* hfinal = out + (size_t)32768 * 512;
    (void)in_sizes; (void)n_in; (void)out_size; (void)ws_size;

    // workspace: ~33.4 MB
    _Float16* p = (_Float16*)d_ws;
    _Float16* e_h = p;    p += 8388608;        // [32768][256]
    _Float16* embW_h = p; p += 65536;          // [256][256]
    _Float16* Wext = p;   p += 5242880;        // [4096][1280]
    _Float16* cWext = p;  p += 655360;         // [512][1280]
    _Float16* hbuf = p;   p += 1048576;        // [32][32][1024]
    _Float16* Hfront = p; p += 2 * kFrontSz;   // [2][32][32][512]
    unsigned* bar = (unsigned*)p;              // [10]
    unsigned* ctr = bar + 10;                  // [63*32]
    float* gred = (float*)(ctr + 63 * 32);     // [63*32*32*2]
    const int kZeroWords = 10 + 63 * 32 + 63 * 32 * 32 * 2;

    k_zero<<<(kZeroWords + 255) / 256, 256, 0, stream>>>(bar, kZeroWords);
    k_cast_f2h<<<64, 256, 0, stream>>>(embW, embW_h, 16384);
    k_pack_wext<<<4096, 256, 0, stream>>>(Wih, Whh, Wext);
    k_pack_cwext<<<512, 256, 0, stream>>>(compW, resW, cWext);
    // e = x @ embW^T + embb : M=32768, N=256, K=256
    k_gemm_a32<<<512, 256, 0, stream>>>(x, embW_h, embb, e_h, 32768, 256, 256, 2);

    k_recur<<<dim3(kNumBlk), dim3(256), 0, stream>>>(
        e_h, Wext, cWext, bih, bhh, compb, resb, lng, lnb,
        hbuf, Hfront, out, hfinal, bar, ctr, gred);
}